// Round 1
// baseline (5065.722 us; speedup 1.0000x reference)
//
#include <hip/hip_runtime.h>
#include <hip/hip_bf16.h>

#define NN  50000
#define EE  300000
#define HH  256
#define TDD 768
#define RRR 200
#define RR2 400
#define NBB 8
#define TTT 8192

// ---------------------------------------------------------------------------
// GEMM: C[M,N] = A[M,K] @ B (+ epilogue)
// BMODE 0: B row-major [N,K]   (B^T GEMM — text projection, W is (H,TD))
// BMODE 1: B "blocked": col n -> basis[n>>8][k][n&255] (basis chunks; root too,
//          since N==256 gives block 0 and addr k*256+n == row-major K x N)
// EPI 0: plain store
// EPI 1: C = acc + add[m,n] + bias[n]                      (text proj epilogue)
// EPI 2: C = relu(acc + add[m,n]*invdeg[m] + bias[n])      (rgcn epilogue)
// ---------------------------------------------------------------------------
template<int BMODE, int EPI>
__global__ __launch_bounds__(256) void gemm_k(
    const float* __restrict__ A, const float* __restrict__ B,
    float* __restrict__ C, int M, int N, int K,
    const float* __restrict__ add, const float* __restrict__ bias,
    const float* __restrict__ invdeg)
{
    __shared__ float As[64][17];   // [m][k], padded
    __shared__ float Bs[16][65];   // [k][n], padded
    const int bm = blockIdx.x * 64;
    const int bn = blockIdx.y * 64;
    const int tid = threadIdx.x;
    const int tx = tid & 15, ty = tid >> 4;

    float acc[4][4] = {};

    for (int k0 = 0; k0 < K; k0 += 16) {
        // ---- load A tile (64 rows x 16 k), float4 per thread ----
        {
            int r  = tid >> 2;
            int kk = (tid & 3) << 2;
            int gm = bm + r;
            float4 v = make_float4(0.f, 0.f, 0.f, 0.f);
            if (gm < M) v = *(const float4*)(A + (size_t)gm * K + k0 + kk);
            As[r][kk]   = v.x; As[r][kk+1] = v.y;
            As[r][kk+2] = v.z; As[r][kk+3] = v.w;
        }
        // ---- load B tile ----
        if (BMODE == 0) {
            int nl = tid >> 2;
            int kk = (tid & 3) << 2;
            float4 v = *(const float4*)(B + (size_t)(bn + nl) * K + k0 + kk);
            Bs[kk][nl]   = v.x; Bs[kk+1][nl] = v.y;
            Bs[kk+2][nl] = v.z; Bs[kk+3][nl] = v.w;
        } else {
            int kk = tid >> 4;
            int nl = (tid & 15) << 2;
            int ng = bn + nl;
            const float* bp = B + (size_t)(ng >> 8) * (HH * HH)
                                + (size_t)(k0 + kk) * HH + (ng & 255);
            float4 v = *(const float4*)bp;
            Bs[kk][nl]   = v.x; Bs[kk][nl+1] = v.y;
            Bs[kk][nl+2] = v.z; Bs[kk][nl+3] = v.w;
        }
        __syncthreads();

#pragma unroll
        for (int k = 0; k < 16; ++k) {
            float a[4], bb[4];
#pragma unroll
            for (int i = 0; i < 4; ++i) a[i]  = As[ty * 4 + i][k];
#pragma unroll
            for (int j = 0; j < 4; ++j) bb[j] = Bs[k][tx * 4 + j];
#pragma unroll
            for (int i = 0; i < 4; ++i)
#pragma unroll
                for (int j = 0; j < 4; ++j)
                    acc[i][j] = fmaf(a[i], bb[j], acc[i][j]);
        }
        __syncthreads();
    }

    // ---- epilogue ----
#pragma unroll
    for (int i = 0; i < 4; ++i) {
        int gm = bm + ty * 4 + i;
        if (gm >= M) continue;
#pragma unroll
        for (int j = 0; j < 4; ++j) {
            int gn = bn + tx * 4 + j;
            float v = acc[i][j];
            if (EPI == 1) v += add[(size_t)gm * N + gn] + bias[gn];
            if (EPI == 2) {
                v = fmaf(add[(size_t)gm * N + gn], invdeg[gm], v) + bias[gn];
                v = fmaxf(v, 0.0f);
            }
            C[(size_t)gm * N + gn] = v;
        }
    }
}

// ---------------------------------------------------------------------------
// LayerNorm over H=256, one wave per row (4 rows per 256-thread block)
// ---------------------------------------------------------------------------
__global__ __launch_bounds__(256) void ln_k(
    const float* __restrict__ in, float* __restrict__ out,
    const float* __restrict__ g, const float* __restrict__ b)
{
    int row  = blockIdx.x * 4 + (threadIdx.x >> 6);
    int lane = threadIdx.x & 63;
    if (row >= NN) return;
    float4 v = *(const float4*)(in + (size_t)row * HH + lane * 4);
    float s = v.x + v.y + v.z + v.w;
#pragma unroll
    for (int o = 1; o < 64; o <<= 1) s += __shfl_xor(s, o);
    float mu = s * (1.0f / HH);
    float dx = v.x - mu, dy = v.y - mu, dz = v.z - mu, dw = v.w - mu;
    float q = dx * dx + dy * dy + dz * dz + dw * dw;
#pragma unroll
    for (int o = 1; o < 64; o <<= 1) q += __shfl_xor(q, o);
    float rstd = rsqrtf(q * (1.0f / HH) + 1e-5f);
    int c = lane * 4;
    float4 o4;
    o4.x = g[c + 0] * dx * rstd + b[c + 0];
    o4.y = g[c + 1] * dy * rstd + b[c + 1];
    o4.z = g[c + 2] * dz * rstd + b[c + 2];
    o4.w = g[c + 3] * dw * rstd + b[c + 3];
    *(float4*)(out + (size_t)row * HH + c) = o4;
}

// ---------------------------------------------------------------------------
// degree / inverse degree
// ---------------------------------------------------------------------------
__global__ void deg_k(const int* __restrict__ dst, float* __restrict__ deg)
{
    int i = blockIdx.x * blockDim.x + threadIdx.x;
    if (i < EE) atomicAdd(&deg[dst[i]], 1.0f);
}

__global__ void invdeg_k(float* __restrict__ deg)
{
    int i = blockIdx.x * blockDim.x + threadIdx.x;
    if (i < NN) deg[i] = 1.0f / fmaxf(deg[i], 1.0f);
}

// ---------------------------------------------------------------------------
// Edge messages: one wave per edge; msg = sum_b c[et,b] * xb[src,b,:] ;
// atomicAdd into agg[dst,:].  xb holds nb basis slices starting at b0.
// ---------------------------------------------------------------------------
__global__ __launch_bounds__(256) void edge_msg_k(
    const float* __restrict__ xb, const float* __restrict__ comp,
    const int* __restrict__ src, const int* __restrict__ dst,
    const int* __restrict__ et, float* __restrict__ agg, int b0, int nb)
{
    int e = blockIdx.x * 4 + (threadIdx.x >> 6);
    if (e >= EE) return;
    int lane = threadIdx.x & 63;
    int s = src[e], d = dst[e], t = et[e];
    const float* xp = xb + (size_t)s * nb * HH + lane * 4;
    float4 acc = make_float4(0.f, 0.f, 0.f, 0.f);
    for (int b = 0; b < nb; ++b) {
        float c  = comp[t * NBB + b0 + b];
        float4 v = *(const float4*)(xp + (size_t)b * HH);
        acc.x = fmaf(c, v.x, acc.x);
        acc.y = fmaf(c, v.y, acc.y);
        acc.z = fmaf(c, v.z, acc.z);
        acc.w = fmaf(c, v.w, acc.w);
    }
    float* ap = agg + (size_t)d * HH + lane * 4;
    atomicAdd(ap + 0, acc.x);
    atomicAdd(ap + 1, acc.y);
    atomicAdd(ap + 2, acc.z);
    atomicAdd(ap + 3, acc.w);
}

// ---------------------------------------------------------------------------
// RotatE/complex-style score, one wave per triple
// ---------------------------------------------------------------------------
__global__ __launch_bounds__(256) void score_k(
    const float* __restrict__ x, const float* __restrict__ rel,
    const int* __restrict__ heads, const int* __restrict__ rels,
    const int* __restrict__ tails, float* __restrict__ out)
{
    int i = blockIdx.x * 4 + (threadIdx.x >> 6);
    if (i >= TTT) return;
    int lane = threadIdx.x & 63;
    const float* h = x   + (size_t)heads[i] * HH;
    const float* t = x   + (size_t)tails[i] * HH;
    const float* r = rel + (size_t)rels[i]  * HH;
    int j = lane * 2;
    float2 hr = *(const float2*)(h + j),       hi = *(const float2*)(h + 128 + j);
    float2 tr = *(const float2*)(t + j),       ti = *(const float2*)(t + 128 + j);
    float2 rr = *(const float2*)(r + j),       ri = *(const float2*)(r + 128 + j);
    float acc = hr.x * rr.x * tr.x + hi.x * rr.x * ti.x
              + hr.x * ri.x * ti.x - hi.x * ri.x * tr.x
              + hr.y * rr.y * tr.y + hi.y * rr.y * ti.y
              + hr.y * ri.y * ti.y - hi.y * ri.y * tr.y;
#pragma unroll
    for (int o = 1; o < 64; o <<= 1) acc += __shfl_xor(acc, o);
    if (lane == 0) out[i] = acc;
}

// ---------------------------------------------------------------------------
extern "C" void kernel_launch(void* const* d_in, const int* in_sizes, int n_in,
                              void* d_out, int out_size, void* d_ws, size_t ws_size,
                              hipStream_t stream)
{
    const float* ent_emb     = (const float*)d_in[0];
    const float* text_base   = (const float*)d_in[1];
    const float* text_proj_w = (const float*)d_in[2];
    const float* text_proj_b = (const float*)d_in[3];
    const float* ln_g        = (const float*)d_in[4];
    const float* ln_b        = (const float*)d_in[5];
    const float* comp1       = (const float*)d_in[6];
    const float* basis1      = (const float*)d_in[7];
    const float* root1       = (const float*)d_in[8];
    const float* bias1       = (const float*)d_in[9];
    const float* comp2       = (const float*)d_in[10];
    const float* basis2      = (const float*)d_in[11];
    const float* root2       = (const float*)d_in[12];
    const float* bias2       = (const float*)d_in[13];
    const float* rel_emb     = (const float*)d_in[14];
    const int*   edge_src    = (const int*)d_in[15];
    const int*   edge_dst    = (const int*)d_in[16];
    const int*   edge_type   = (const int*)d_in[17];
    const int*   heads       = (const int*)d_in[18];
    const int*   rels        = (const int*)d_in[19];
    const int*   tails       = (const int*)d_in[20];
    float* out = (float*)d_out;

    // workspace carve-up (256B aligned)
    char* ws = (char*)d_ws;
    size_t off = 0;
    auto carve = [&](size_t bytes) -> void* {
        void* p = ws + off;
        off = (off + bytes + 255) & ~(size_t)255;
        return p;
    };
    float* x0  = (float*)carve((size_t)NN * HH * 4);
    float* x1  = (float*)carve((size_t)NN * HH * 4);
    float* agg = (float*)carve((size_t)NN * HH * 4);
    float* deg = (float*)carve((size_t)NN * 4);
    size_t rem = (ws_size > off) ? (ws_size - off) : 0;
    int nbc = (int)(rem / ((size_t)NN * HH * 4));
    if (nbc > NBB) nbc = NBB;
    if (nbc < 1)  nbc = 1;           // minimum-footprint fallback
    float* xb = (float*)(ws + off);

    const dim3 blk(256);
    const dim3 gemm_grid_h((NN + 63) / 64, HH / 64);   // 782 x 4

    // degree (shared by both layers)
    hipMemsetAsync(deg, 0, (size_t)NN * 4, stream);
    deg_k<<<(EE + 255) / 256, blk, 0, stream>>>(edge_dst, deg);
    invdeg_k<<<(NN + 255) / 256, blk, 0, stream>>>(deg);

    // x_pre = ent_emb + text_base @ W^T + b   ->   x0 = LN(x_pre)
    gemm_k<0, 1><<<gemm_grid_h, blk, 0, stream>>>(
        text_base, text_proj_w, x1, NN, HH, TDD, ent_emb, text_proj_b, nullptr);
    ln_k<<<NN / 4, blk, 0, stream>>>(x1, x0, ln_g, ln_b);

    // two RGCN layers
    for (int layer = 0; layer < 2; ++layer) {
        const float* xin   = layer ? x1 : x0;
        float*       xout  = layer ? x0 : x1;
        const float* basis = layer ? basis2 : basis1;
        const float* comp  = layer ? comp2  : comp1;
        const float* root  = layer ? root2  : root1;
        const float* bias  = layer ? bias2  : bias1;

        hipMemsetAsync(agg, 0, (size_t)NN * HH * 4, stream);
        for (int b0 = 0; b0 < NBB; b0 += nbc) {
            int nb = (NBB - b0 < nbc) ? (NBB - b0) : nbc;
            gemm_k<1, 0><<<dim3((NN + 63) / 64, nb * HH / 64), blk, 0, stream>>>(
                xin, basis + (size_t)b0 * HH * HH, xb, NN, nb * HH, HH,
                nullptr, nullptr, nullptr);
            edge_msg_k<<<(EE + 3) / 4, blk, 0, stream>>>(
                xb, comp, edge_src, edge_dst, edge_type, agg, b0, nb);
        }
        gemm_k<1, 2><<<gemm_grid_h, blk, 0, stream>>>(
            xin, root, xout, NN, HH, HH, agg, bias, deg);
    }

    // scoring (x0 holds the final representation after layer 2)
    score_k<<<TTT / 4, blk, 0, stream>>>(x0, rel_emb, heads, rels, tails, out);
}

// Round 2
// 2476.075 us; speedup vs baseline: 2.0459x; 2.0459x over previous
//
#include <hip/hip_runtime.h>
#include <hip/hip_bf16.h>

#define NN  50000
#define EE  300000
#define HH  256
#define TDD 768
#define NBB 8
#define TTT 8192

// ---------------------------------------------------------------------------
// GEMM: C[M,256] = A[M,K] @ B[K,256] (+ epilogue).  BN=256 (full row), BM=64,
// BK=16, 256 threads, 8x8 micro-tile per thread.
// A is split at KS: k<KS from A1 (lda1), else A2 (lda2) at k-KS.
// BMODE 0: B1 is [256][K] row-major (W; computes A @ W^T). B2 unused.
// BMODE 1: B row-major [K][256]: k<KS from B1 (basis, contiguous [8,256,256]
//          == [2048,256]), else B2 (root) at k-KS.
// EPI 1: C = acc + add[m,n] + bias[n]          (text proj + ent_emb)
// EPI 2: C = relu(acc + bias[n])               (rgcn layer out)
// ---------------------------------------------------------------------------
template<int BMODE, int EPI>
__global__ __launch_bounds__(256, 4) void gemm_k(
    const float* __restrict__ A1, int lda1,
    const float* __restrict__ A2, int lda2, int KS,
    const float* __restrict__ B1, const float* __restrict__ B2,
    float* __restrict__ C, int M, int K,
    const float* __restrict__ add, const float* __restrict__ bias)
{
    __shared__ float As[16][72];    // [k][m], stride 72 floats (288B, 16B-mult)
    __shared__ float Bs[16][264];   // [k][n], stride 264 floats (1056B)
    const int tid = threadIdx.x;
    const int bm  = blockIdx.x * 64;
    const int tx  = tid & 31;       // n-group: cols tx*4..+3 and 128+tx*4..+3
    const int ty  = tid >> 5;       // m-group: rows ty*8..+7

    float acc[8][8] = {};

    for (int k0 = 0; k0 < K; k0 += 16) {
        // ---- stage A tile: As[kk][m] = A[bm+m][k0+kk] ----
        {
            const float* Ap; int lda, kb;
            if (k0 < KS) { Ap = A1; lda = lda1; kb = k0; }
            else         { Ap = A2; lda = lda2; kb = k0 - KS; }
            int m  = tid >> 2;
            int k4 = (tid & 3) << 2;
            int gm = bm + m;
            float4 v = make_float4(0.f, 0.f, 0.f, 0.f);
            if (gm < M) v = *(const float4*)(Ap + (size_t)gm * lda + kb + k4);
            As[k4+0][m] = v.x; As[k4+1][m] = v.y;
            As[k4+2][m] = v.z; As[k4+3][m] = v.w;
        }
        // ---- stage B tile: Bs[kk][n] ----
        if (BMODE == 0) {
            int n = tid;                                  // W[n][k0..k0+15]
            const float* bp = B1 + (size_t)n * K + k0;
            float4 v0 = *(const float4*)(bp + 0);
            float4 v1 = *(const float4*)(bp + 4);
            float4 v2 = *(const float4*)(bp + 8);
            float4 v3 = *(const float4*)(bp + 12);
            Bs[ 0][n]=v0.x; Bs[ 1][n]=v0.y; Bs[ 2][n]=v0.z; Bs[ 3][n]=v0.w;
            Bs[ 4][n]=v1.x; Bs[ 5][n]=v1.y; Bs[ 6][n]=v1.z; Bs[ 7][n]=v1.w;
            Bs[ 8][n]=v2.x; Bs[ 9][n]=v2.y; Bs[10][n]=v2.z; Bs[11][n]=v2.w;
            Bs[12][n]=v3.x; Bs[13][n]=v3.y; Bs[14][n]=v3.z; Bs[15][n]=v3.w;
        } else {
            const float* Bp = (k0 < KS) ? (B1 + (size_t)k0 * HH)
                                        : (B2 + (size_t)(k0 - KS) * HH);
            int kk = tid >> 4;
            int n0 = (tid & 15) << 4;
            const float* bp = Bp + (size_t)kk * HH + n0;
            float4 v0 = *(const float4*)(bp + 0);
            float4 v1 = *(const float4*)(bp + 4);
            float4 v2 = *(const float4*)(bp + 8);
            float4 v3 = *(const float4*)(bp + 12);
            *(float4*)&Bs[kk][n0 + 0]  = v0;
            *(float4*)&Bs[kk][n0 + 4]  = v1;
            *(float4*)&Bs[kk][n0 + 8]  = v2;
            *(float4*)&Bs[kk][n0 + 12] = v3;
        }
        __syncthreads();

#pragma unroll
        for (int kk = 0; kk < 16; ++kk) {
            float4 a0 = *(const float4*)&As[kk][ty * 8];
            float4 a1 = *(const float4*)&As[kk][ty * 8 + 4];
            float4 b0 = *(const float4*)&Bs[kk][tx * 4];
            float4 b1 = *(const float4*)&Bs[kk][tx * 4 + 128];
            float a[8] = {a0.x,a0.y,a0.z,a0.w,a1.x,a1.y,a1.z,a1.w};
            float b[8] = {b0.x,b0.y,b0.z,b0.w,b1.x,b1.y,b1.z,b1.w};
#pragma unroll
            for (int i = 0; i < 8; ++i)
#pragma unroll
                for (int j = 0; j < 8; ++j)
                    acc[i][j] = fmaf(a[i], b[j], acc[i][j]);
        }
        __syncthreads();
    }

    // ---- epilogue ----
#pragma unroll
    for (int i = 0; i < 8; ++i) {
        int gm = bm + ty * 8 + i;
        if (gm >= M) continue;
        int gn0 = tx * 4, gn1 = 128 + tx * 4;
        float4 r0 = make_float4(acc[i][0], acc[i][1], acc[i][2], acc[i][3]);
        float4 r1 = make_float4(acc[i][4], acc[i][5], acc[i][6], acc[i][7]);
        float4 bb0 = *(const float4*)(bias + gn0);
        float4 bb1 = *(const float4*)(bias + gn1);
        if (EPI == 1) {
            float4 e0 = *(const float4*)(add + (size_t)gm * HH + gn0);
            float4 e1 = *(const float4*)(add + (size_t)gm * HH + gn1);
            r0.x += e0.x + bb0.x; r0.y += e0.y + bb0.y;
            r0.z += e0.z + bb0.z; r0.w += e0.w + bb0.w;
            r1.x += e1.x + bb1.x; r1.y += e1.y + bb1.y;
            r1.z += e1.z + bb1.z; r1.w += e1.w + bb1.w;
        }
        if (EPI == 2) {
            r0.x = fmaxf(r0.x + bb0.x, 0.f); r0.y = fmaxf(r0.y + bb0.y, 0.f);
            r0.z = fmaxf(r0.z + bb0.z, 0.f); r0.w = fmaxf(r0.w + bb0.w, 0.f);
            r1.x = fmaxf(r1.x + bb1.x, 0.f); r1.y = fmaxf(r1.y + bb1.y, 0.f);
            r1.z = fmaxf(r1.z + bb1.z, 0.f); r1.w = fmaxf(r1.w + bb1.w, 0.f);
        }
        *(float4*)(C + (size_t)gm * HH + gn0) = r0;
        *(float4*)(C + (size_t)gm * HH + gn1) = r1;
    }
}

// ---------------------------------------------------------------------------
// LayerNorm over H=256, one wave per row
// ---------------------------------------------------------------------------
__global__ __launch_bounds__(256) void ln_k(
    const float* __restrict__ in, float* __restrict__ out,
    const float* __restrict__ g, const float* __restrict__ b)
{
    int row  = blockIdx.x * 4 + (threadIdx.x >> 6);
    int lane = threadIdx.x & 63;
    if (row >= NN) return;
    float4 v = *(const float4*)(in + (size_t)row * HH + lane * 4);
    float s = v.x + v.y + v.z + v.w;
#pragma unroll
    for (int o = 1; o < 64; o <<= 1) s += __shfl_xor(s, o);
    float mu = s * (1.0f / HH);
    float dx = v.x - mu, dy = v.y - mu, dz = v.z - mu, dw = v.w - mu;
    float q = dx * dx + dy * dy + dz * dz + dw * dw;
#pragma unroll
    for (int o = 1; o < 64; o <<= 1) q += __shfl_xor(q, o);
    float rstd = rsqrtf(q * (1.0f / HH) + 1e-5f);
    int c = lane * 4;
    float4 o4;
    o4.x = g[c + 0] * dx * rstd + b[c + 0];
    o4.y = g[c + 1] * dy * rstd + b[c + 1];
    o4.z = g[c + 2] * dz * rstd + b[c + 2];
    o4.w = g[c + 3] * dw * rstd + b[c + 3];
    *(float4*)(out + (size_t)row * HH + c) = o4;
}

// ---------------------------------------------------------------------------
// CSR build: histogram -> block scans -> scatter
// ---------------------------------------------------------------------------
__global__ void hist_k(const int* __restrict__ dst, int* __restrict__ cnt)
{
    int i = blockIdx.x * blockDim.x + threadIdx.x;
    if (i < EE) atomicAdd(&cnt[dst[i]], 1);
}

__global__ void scan_blk_k(const int* __restrict__ cnt, int* __restrict__ rp,
                           int* __restrict__ bsum)
{
    __shared__ int s[256];
    int tid = threadIdx.x;
    int d = blockIdx.x * 256 + tid;
    int v = (d < NN) ? cnt[d] : 0;
    s[tid] = v;
    __syncthreads();
#pragma unroll
    for (int o = 1; o < 256; o <<= 1) {
        int t = (tid >= o) ? s[tid - o] : 0;
        __syncthreads();
        s[tid] += t;
        __syncthreads();
    }
    if (d < NN) rp[d] = s[tid] - v;              // exclusive within block
    if (tid == 255) bsum[blockIdx.x] = s[255];
}

__global__ void scan_top_k(int* __restrict__ bsum, int* __restrict__ boff, int nb)
{
    __shared__ int s[256];
    int tid = threadIdx.x;
    int v = (tid < nb) ? bsum[tid] : 0;
    s[tid] = v;
    __syncthreads();
#pragma unroll
    for (int o = 1; o < 256; o <<= 1) {
        int t = (tid >= o) ? s[tid - o] : 0;
        __syncthreads();
        s[tid] += t;
        __syncthreads();
    }
    if (tid < nb) boff[tid] = s[tid] - v;        // exclusive
}

__global__ void scan_add_k(int* __restrict__ rp, const int* __restrict__ boff,
                           int* __restrict__ cur, const int* __restrict__ cnt,
                           float* __restrict__ invdeg)
{
    int d = blockIdx.x * blockDim.x + threadIdx.x;
    if (d < NN) {
        int r = rp[d] + boff[d >> 8];
        rp[d] = r;
        cur[d] = r;
        invdeg[d] = 1.0f / fmaxf((float)cnt[d], 1.0f);
    }
    if (d == 0) rp[NN] = EE;
}

__global__ void scatter_k(const int* __restrict__ src, const int* __restrict__ dst,
                          const int* __restrict__ et, int* __restrict__ cur,
                          int* __restrict__ csr_src, int* __restrict__ csr_et)
{
    int e = blockIdx.x * blockDim.x + threadIdx.x;
    if (e >= EE) return;
    int p = atomicAdd(&cur[dst[e]], 1);
    csr_src[p] = src[e];
    csr_et[p]  = et[e];
}

// ---------------------------------------------------------------------------
// Aggregation: one wave per dst node d.
// y[d, b*256 + :] = invdeg[d] * sum_{e in-edges} comp[et_e][b] * x[src_e, :]
// ---------------------------------------------------------------------------
__global__ __launch_bounds__(256) void agg_k(
    const float* __restrict__ x, const float* __restrict__ comp,
    const int* __restrict__ rp, const int* __restrict__ csr_src,
    const int* __restrict__ csr_et, const float* __restrict__ invdeg,
    float* __restrict__ y)
{
    int d = blockIdx.x * 4 + (threadIdx.x >> 6);
    if (d >= NN) return;
    int lane = threadIdx.x & 63;
    int beg = rp[d], end = rp[d + 1];

    float4 acc[NBB];
#pragma unroll
    for (int b = 0; b < NBB; ++b) acc[b] = make_float4(0.f, 0.f, 0.f, 0.f);

    for (int e = beg; e < end; ++e) {
        int s = csr_src[e];
        int t = csr_et[e];
        float4 c0 = *(const float4*)(comp + (size_t)t * NBB);
        float4 c1 = *(const float4*)(comp + (size_t)t * NBB + 4);
        float4 xv = *(const float4*)(x + (size_t)s * HH + lane * 4);
        float cc[NBB] = {c0.x, c0.y, c0.z, c0.w, c1.x, c1.y, c1.z, c1.w};
#pragma unroll
        for (int b = 0; b < NBB; ++b) {
            acc[b].x = fmaf(cc[b], xv.x, acc[b].x);
            acc[b].y = fmaf(cc[b], xv.y, acc[b].y);
            acc[b].z = fmaf(cc[b], xv.z, acc[b].z);
            acc[b].w = fmaf(cc[b], xv.w, acc[b].w);
        }
    }
    float sc = invdeg[d];
    float* yp = y + (size_t)d * (NBB * HH) + lane * 4;
#pragma unroll
    for (int b = 0; b < NBB; ++b) {
        float4 o;
        o.x = acc[b].x * sc; o.y = acc[b].y * sc;
        o.z = acc[b].z * sc; o.w = acc[b].w * sc;
        *(float4*)(yp + (size_t)b * HH) = o;
    }
}

// ---------------------------------------------------------------------------
// RotatE/complex-style score, one wave per triple
// ---------------------------------------------------------------------------
__global__ __launch_bounds__(256) void score_k(
    const float* __restrict__ x, const float* __restrict__ rel,
    const int* __restrict__ heads, const int* __restrict__ rels,
    const int* __restrict__ tails, float* __restrict__ out)
{
    int i = blockIdx.x * 4 + (threadIdx.x >> 6);
    if (i >= TTT) return;
    int lane = threadIdx.x & 63;
    const float* h = x   + (size_t)heads[i] * HH;
    const float* t = x   + (size_t)tails[i] * HH;
    const float* r = rel + (size_t)rels[i]  * HH;
    int j = lane * 2;
    float2 hr = *(const float2*)(h + j), hi = *(const float2*)(h + 128 + j);
    float2 tr = *(const float2*)(t + j), ti = *(const float2*)(t + 128 + j);
    float2 rr = *(const float2*)(r + j), ri = *(const float2*)(r + 128 + j);
    float acc = hr.x * rr.x * tr.x + hi.x * rr.x * ti.x
              + hr.x * ri.x * ti.x - hi.x * ri.x * tr.x
              + hr.y * rr.y * tr.y + hi.y * rr.y * ti.y
              + hr.y * ri.y * ti.y - hi.y * ri.y * tr.y;
#pragma unroll
    for (int o = 1; o < 64; o <<= 1) acc += __shfl_xor(acc, o);
    if (lane == 0) out[i] = acc;
}

// ---------------------------------------------------------------------------
extern "C" void kernel_launch(void* const* d_in, const int* in_sizes, int n_in,
                              void* d_out, int out_size, void* d_ws, size_t ws_size,
                              hipStream_t stream)
{
    const float* ent_emb     = (const float*)d_in[0];
    const float* text_base   = (const float*)d_in[1];
    const float* text_proj_w = (const float*)d_in[2];
    const float* text_proj_b = (const float*)d_in[3];
    const float* ln_g        = (const float*)d_in[4];
    const float* ln_b        = (const float*)d_in[5];
    const float* comp1       = (const float*)d_in[6];
    const float* basis1      = (const float*)d_in[7];
    const float* root1       = (const float*)d_in[8];
    const float* bias1       = (const float*)d_in[9];
    const float* comp2       = (const float*)d_in[10];
    const float* basis2      = (const float*)d_in[11];
    const float* root2       = (const float*)d_in[12];
    const float* bias2       = (const float*)d_in[13];
    const float* rel_emb     = (const float*)d_in[14];
    const int*   edge_src    = (const int*)d_in[15];
    const int*   edge_dst    = (const int*)d_in[16];
    const int*   edge_type   = (const int*)d_in[17];
    const int*   heads       = (const int*)d_in[18];
    const int*   rels        = (const int*)d_in[19];
    const int*   tails       = (const int*)d_in[20];
    float* out = (float*)d_out;

    // workspace carve-up (256B aligned)
    char* ws = (char*)d_ws;
    size_t off = 0;
    auto carve = [&](size_t bytes) -> void* {
        void* p = ws + off;
        off = (off + bytes + 255) & ~(size_t)255;
        return p;
    };
    float* x0      = (float*)carve((size_t)NN * HH * 4);
    float* x1      = (float*)carve((size_t)NN * HH * 4);
    float* y       = (float*)carve((size_t)NN * NBB * HH * 4);   // 410 MB
    int*   cnt     = (int*)  carve((size_t)NN * 4);
    int*   rp      = (int*)  carve((size_t)(NN + 1) * 4);
    int*   cur     = (int*)  carve((size_t)NN * 4);
    float* invdeg  = (float*)carve((size_t)NN * 4);
    int*   csr_src = (int*)  carve((size_t)EE * 4);
    int*   csr_et  = (int*)  carve((size_t)EE * 4);
    int*   bsum    = (int*)  carve(256 * 4);
    int*   boff    = (int*)  carve(256 * 4);

    const dim3 blk(256);
    const int NBLK = (NN + 255) / 256;          // 196 scan blocks
    const int GEMM_GRID = (NN + 63) / 64;       // 782

    // ---- CSR build (shared by both layers) ----
    hipMemsetAsync(cnt, 0, (size_t)NN * 4, stream);
    hist_k<<<(EE + 255) / 256, blk, 0, stream>>>(edge_dst, cnt);
    scan_blk_k<<<NBLK, blk, 0, stream>>>(cnt, rp, bsum);
    scan_top_k<<<1, blk, 0, stream>>>(bsum, boff, NBLK);
    scan_add_k<<<NBLK, blk, 0, stream>>>(rp, boff, cur, cnt, invdeg);
    scatter_k<<<(EE + 255) / 256, blk, 0, stream>>>(
        edge_src, edge_dst, edge_type, cur, csr_src, csr_et);

    // ---- x1 = text_base @ W^T + ent_emb + b ;  x0 = LN(x1) ----
    gemm_k<0, 1><<<GEMM_GRID, blk, 0, stream>>>(
        text_base, TDD, text_base, TDD, TDD,
        text_proj_w, nullptr, x1, NN, TDD, ent_emb, text_proj_b);
    ln_k<<<(NN + 3) / 4, blk, 0, stream>>>(x1, x0, ln_g, ln_b);

    // ---- two RGCN layers ----
    for (int layer = 0; layer < 2; ++layer) {
        const float* xin   = layer ? x1 : x0;
        float*       xout  = layer ? x0 : x1;
        const float* basis = layer ? basis2 : basis1;
        const float* comp  = layer ? comp2  : comp1;
        const float* root  = layer ? root2  : root1;
        const float* bias  = layer ? bias2  : bias1;

        agg_k<<<(NN + 3) / 4, blk, 0, stream>>>(
            xin, comp, rp, csr_src, csr_et, invdeg, y);

        // xout = relu( y @ Bcat + xin @ root + bias ), K = 2048 + 256
        gemm_k<1, 2><<<GEMM_GRID, blk, 0, stream>>>(
            y, NBB * HH, xin, HH, NBB * HH,
            basis, root, xout, NN, NBB * HH + HH, nullptr, bias);
    }

    // ---- scoring ----
    score_k<<<(TTT + 3) / 4, blk, 0, stream>>>(x0, rel_emb, heads, rels, tails, out);
}

// Round 3
// 1023.706 us; speedup vs baseline: 4.9484x; 2.4187x over previous
//
#include <hip/hip_runtime.h>
#include <hip/hip_bf16.h>

#define NN  50000
#define EE  300000
#define HH  256
#define TDD 768
#define NBB 8
#define TTT 8192

typedef __bf16 bf16x8 __attribute__((ext_vector_type(8)));
typedef float  f32x4  __attribute__((ext_vector_type(4)));

__device__ __forceinline__ float b2f(unsigned short u) {
    union { unsigned int i; float f; } v; v.i = (unsigned int)u << 16; return v.f;
}
__device__ __forceinline__ unsigned short f2b(float f) {
    union { float f; unsigned int i; } v; v.f = f;
    unsigned int r = (v.i + 0x7fffu + ((v.i >> 16) & 1u)) >> 16;
    return (unsigned short)r;
}
__device__ __forceinline__ void gload16(const void* g, void* l) {
    __builtin_amdgcn_global_load_lds(
        (const __attribute__((address_space(1))) void*)g,
        (__attribute__((address_space(3))) void*)l, 16, 0, 0);
}

// ---------------------------------------------------------------------------
// bf16 MFMA GEMM: C[M,256](bf16) = A[M,K](bf16) @ Bt[256,K](bf16)^T + epi
// A split at KS: k<KS from A1(lda1) else A2(lda2, k-KS).
// 128x128 tile, 4 waves (2x2 of 64x64), BK=32, 16x16x32 MFMA.
// LDS chunk-major panels: elem[cg*1024 + r*8 + e] = T[row r][k0 + cg*8 + e].
// EPI 1: C = acc + add[m,n] + bias[n]      EPI 2: C = relu(acc + bias[n])
// ---------------------------------------------------------------------------
template<int EPI>
__global__ __launch_bounds__(256) void gemm16_k(
    const unsigned short* __restrict__ A1, int lda1,
    const unsigned short* __restrict__ A2, int lda2, int KS,
    const unsigned short* __restrict__ Bt, int K,
    unsigned short* __restrict__ C, int M,
    const float* __restrict__ add, const float* __restrict__ bias)
{
    __shared__ unsigned short As[4096];   // 8 KB
    __shared__ unsigned short Bs[4096];   // 8 KB
    const int tid  = threadIdx.x;
    const int lane = tid & 63;
    const int wid  = tid >> 6;
    const int bm   = blockIdx.x * 128;
    const int bn   = blockIdx.y * 128;
    const int lrow = lane & 15;
    const int lk   = lane >> 4;
    const int wm   = (wid & 1) * 64;
    const int wn   = (wid >> 1) * 64;

    f32x4 acc[4][4];
#pragma unroll
    for (int i = 0; i < 4; ++i)
#pragma unroll
        for (int j = 0; j < 4; ++j) acc[i][j] = (f32x4){0.f, 0.f, 0.f, 0.f};

    for (int k0 = 0; k0 < K; k0 += 32) {
        const unsigned short* Ap; int lda, kb;
        if (k0 < KS) { Ap = A1; lda = lda1; kb = k0; }
        else         { Ap = A2; lda = lda2; kb = k0 - KS; }
#pragma unroll
        for (int p = 0; p < 2; ++p) {
            int cbar = p * 4 + wid;           // wave-chunk 0..7
            int s  = cbar * 64 + lane;        // 16B slot
            int cg = s >> 7, r = s & 127;
            int gm = bm + r; if (gm >= M) gm = M - 1;
            gload16(Ap + (size_t)gm * lda + kb + cg * 8, &As[cbar * 512]);
            gload16(Bt + (size_t)(bn + r) * K + k0 + cg * 8, &Bs[cbar * 512]);
        }
        __syncthreads();

        bf16x8 af[4], bfr[4];
#pragma unroll
        for (int i = 0; i < 4; ++i) {
            af[i]  = *(const bf16x8*)&As[lk * 1024 + (wm + i * 16 + lrow) * 8];
            bfr[i] = *(const bf16x8*)&Bs[lk * 1024 + (wn + i * 16 + lrow) * 8];
        }
#pragma unroll
        for (int i = 0; i < 4; ++i)
#pragma unroll
            for (int j = 0; j < 4; ++j)
                acc[i][j] = __builtin_amdgcn_mfma_f32_16x16x32_bf16(
                    af[i], bfr[j], acc[i][j], 0, 0, 0);
        __syncthreads();
    }

    // epilogue: row = (lane>>4)*4 + e, col = lane&15 within each 16x16 frag
#pragma unroll
    for (int i = 0; i < 4; ++i) {
        int row0 = bm + wm + i * 16 + lk * 4;
#pragma unroll
        for (int j = 0; j < 4; ++j) {
            int col = bn + wn + j * 16 + lrow;
            float bb = bias[col];
            f32x4 v = acc[i][j];
#pragma unroll
            for (int e = 0; e < 4; ++e) {
                int gm = row0 + e;
                if (gm < M) {
                    float o = v[e] + bb;
                    if (EPI == 1) o += add[(size_t)gm * HH + col];
                    if (EPI == 2) o = fmaxf(o, 0.f);
                    C[(size_t)gm * HH + col] = f2b(o);
                }
            }
        }
    }
}

// ---------------------------------------------------------------------------
// casts
// ---------------------------------------------------------------------------
__global__ void cast4_k(const float* __restrict__ in, unsigned short* __restrict__ out,
                        int n4)
{
    int i = blockIdx.x * blockDim.x + threadIdx.x;
    if (i >= n4) return;
    float4 v = *(const float4*)(in + (size_t)i * 4);
    ushort4 o;
    o.x = f2b(v.x); o.y = f2b(v.y); o.z = f2b(v.z); o.w = f2b(v.w);
    *(ushort4*)(out + (size_t)i * 4) = o;
}

// transpose-cast basis/root into Bt[256][2304] per layer
__global__ __launch_bounds__(256) void tcast_k(
    const float* __restrict__ basis1, const float* __restrict__ root1,
    const float* __restrict__ basis2, const float* __restrict__ root2,
    unsigned short* __restrict__ Bt1, unsigned short* __restrict__ Bt2)
{
    __shared__ float Ls[64][68];
    int z = blockIdx.z;
    int layer = z / 9, m = z % 9;
    const float* src = layer ? (m < 8 ? basis2 + m * 65536 : root2)
                             : (m < 8 ? basis1 + m * 65536 : root1);
    unsigned short* dst = layer ? Bt2 : Bt1;
    int coloff = (m < 8) ? m * 256 : 2048;
    int ft = blockIdx.x * 64, dt = blockIdx.y * 64;
    int tid = threadIdx.x;
    int rr = tid >> 4, c4 = (tid & 15) << 2;
#pragma unroll
    for (int p = 0; p < 4; ++p) {
        int dl = p * 16 + rr;
        float4 v = *(const float4*)(src + (size_t)(dt + dl) * HH + ft + c4);
        Ls[c4 + 0][dl] = v.x; Ls[c4 + 1][dl] = v.y;
        Ls[c4 + 2][dl] = v.z; Ls[c4 + 3][dl] = v.w;
    }
    __syncthreads();
#pragma unroll
    for (int q = 0; q < 4; ++q) {
        int fl = q * 16 + rr;
        ushort4 o;
        o.x = f2b(Ls[fl][c4 + 0]); o.y = f2b(Ls[fl][c4 + 1]);
        o.z = f2b(Ls[fl][c4 + 2]); o.w = f2b(Ls[fl][c4 + 3]);
        *(ushort4*)(dst + (size_t)(ft + fl) * 2304 + coloff + dt + c4) = o;
    }
}

// ---------------------------------------------------------------------------
// LayerNorm (bf16 in/out)
// ---------------------------------------------------------------------------
__global__ __launch_bounds__(256) void ln_k(
    const unsigned short* __restrict__ in, unsigned short* __restrict__ out,
    const float* __restrict__ g, const float* __restrict__ b)
{
    int row  = blockIdx.x * 4 + (threadIdx.x >> 6);
    int lane = threadIdx.x & 63;
    if (row >= NN) return;
    ushort4 u = *(const ushort4*)(in + (size_t)row * HH + lane * 4);
    float x0 = b2f(u.x), x1 = b2f(u.y), x2 = b2f(u.z), x3 = b2f(u.w);
    float s = x0 + x1 + x2 + x3;
#pragma unroll
    for (int o = 1; o < 64; o <<= 1) s += __shfl_xor(s, o);
    float mu = s * (1.0f / HH);
    float d0 = x0 - mu, d1 = x1 - mu, d2 = x2 - mu, d3 = x3 - mu;
    float q = d0 * d0 + d1 * d1 + d2 * d2 + d3 * d3;
#pragma unroll
    for (int o = 1; o < 64; o <<= 1) q += __shfl_xor(q, o);
    float rstd = rsqrtf(q * (1.0f / HH) + 1e-5f);
    int c = lane * 4;
    ushort4 o4;
    o4.x = f2b(g[c + 0] * d0 * rstd + b[c + 0]);
    o4.y = f2b(g[c + 1] * d1 * rstd + b[c + 1]);
    o4.z = f2b(g[c + 2] * d2 * rstd + b[c + 2]);
    o4.w = f2b(g[c + 3] * d3 * rstd + b[c + 3]);
    *(ushort4*)(out + (size_t)row * HH + c) = o4;
}

// ---------------------------------------------------------------------------
// CSR build
// ---------------------------------------------------------------------------
__global__ void hist_k(const int* __restrict__ dst, int* __restrict__ cnt)
{
    int i = blockIdx.x * blockDim.x + threadIdx.x;
    if (i < EE) atomicAdd(&cnt[dst[i]], 1);
}

__global__ void scan_blk_k(const int* __restrict__ cnt, int* __restrict__ rp,
                           int* __restrict__ bsum)
{
    __shared__ int s[256];
    int tid = threadIdx.x;
    int d = blockIdx.x * 256 + tid;
    int v = (d < NN) ? cnt[d] : 0;
    s[tid] = v;
    __syncthreads();
#pragma unroll
    for (int o = 1; o < 256; o <<= 1) {
        int t = (tid >= o) ? s[tid - o] : 0;
        __syncthreads();
        s[tid] += t;
        __syncthreads();
    }
    if (d < NN) rp[d] = s[tid] - v;
    if (tid == 255) bsum[blockIdx.x] = s[255];
}

__global__ void scan_top_k(int* __restrict__ bsum, int* __restrict__ boff, int nb)
{
    __shared__ int s[256];
    int tid = threadIdx.x;
    int v = (tid < nb) ? bsum[tid] : 0;
    s[tid] = v;
    __syncthreads();
#pragma unroll
    for (int o = 1; o < 256; o <<= 1) {
        int t = (tid >= o) ? s[tid - o] : 0;
        __syncthreads();
        s[tid] += t;
        __syncthreads();
    }
    if (tid < nb) boff[tid] = s[tid] - v;
}

__global__ void scan_add_k(int* __restrict__ rp, const int* __restrict__ boff,
                           int* __restrict__ cur, const int* __restrict__ cnt,
                           float* __restrict__ invdeg)
{
    int d = blockIdx.x * blockDim.x + threadIdx.x;
    if (d < NN) {
        int r = rp[d] + boff[d >> 8];
        rp[d] = r;
        cur[d] = r;
        invdeg[d] = 1.0f / fmaxf((float)cnt[d], 1.0f);
    }
    if (d == 0) rp[NN] = EE;
}

__global__ void scatter_k(const int* __restrict__ src, const int* __restrict__ dst,
                          const int* __restrict__ et, int* __restrict__ cur,
                          int* __restrict__ csr_src, int* __restrict__ csr_et)
{
    int e = blockIdx.x * blockDim.x + threadIdx.x;
    if (e >= EE) return;
    int p = atomicAdd(&cur[dst[e]], 1);
    csr_src[p] = src[e];
    csr_et[p]  = et[e];
}

// ---------------------------------------------------------------------------
// Aggregation (bf16 x -> bf16 y), one wave per dst node
// y[d, b*256+c] = invdeg[d] * sum_e comp[et_e][b] * x[src_e, c]
// ---------------------------------------------------------------------------
__global__ __launch_bounds__(256) void agg_k(
    const unsigned short* __restrict__ x, const float* __restrict__ comp,
    const int* __restrict__ rp, const int* __restrict__ csr_src,
    const int* __restrict__ csr_et, const float* __restrict__ invdeg,
    unsigned short* __restrict__ y)
{
    int d = blockIdx.x * 4 + (threadIdx.x >> 6);
    if (d >= NN) return;
    int lane = threadIdx.x & 63;
    int beg = rp[d], end = rp[d + 1];

    float4 acc[NBB];
#pragma unroll
    for (int b = 0; b < NBB; ++b) acc[b] = make_float4(0.f, 0.f, 0.f, 0.f);

    for (int e = beg; e < end; ++e) {
        int s = csr_src[e];
        int t = csr_et[e];
        float4 c0 = *(const float4*)(comp + (size_t)t * NBB);
        float4 c1 = *(const float4*)(comp + (size_t)t * NBB + 4);
        ushort4 u = *(const ushort4*)(x + (size_t)s * HH + lane * 4);
        float xv0 = b2f(u.x), xv1 = b2f(u.y), xv2 = b2f(u.z), xv3 = b2f(u.w);
        float cc[NBB] = {c0.x, c0.y, c0.z, c0.w, c1.x, c1.y, c1.z, c1.w};
#pragma unroll
        for (int b = 0; b < NBB; ++b) {
            acc[b].x = fmaf(cc[b], xv0, acc[b].x);
            acc[b].y = fmaf(cc[b], xv1, acc[b].y);
            acc[b].z = fmaf(cc[b], xv2, acc[b].z);
            acc[b].w = fmaf(cc[b], xv3, acc[b].w);
        }
    }
    float sc = invdeg[d];
    unsigned short* yp = y + (size_t)d * (NBB * HH) + lane * 4;
#pragma unroll
    for (int b = 0; b < NBB; ++b) {
        ushort4 o;
        o.x = f2b(acc[b].x * sc); o.y = f2b(acc[b].y * sc);
        o.z = f2b(acc[b].z * sc); o.w = f2b(acc[b].w * sc);
        *(ushort4*)(yp + (size_t)b * HH) = o;
    }
}

// ---------------------------------------------------------------------------
// score (bf16 x, f32 rel)
// ---------------------------------------------------------------------------
__global__ __launch_bounds__(256) void score_k(
    const unsigned short* __restrict__ x, const float* __restrict__ rel,
    const int* __restrict__ heads, const int* __restrict__ rels,
    const int* __restrict__ tails, float* __restrict__ out)
{
    int i = blockIdx.x * 4 + (threadIdx.x >> 6);
    if (i >= TTT) return;
    int lane = threadIdx.x & 63;
    const unsigned short* h = x + (size_t)heads[i] * HH;
    const unsigned short* t = x + (size_t)tails[i] * HH;
    const float*          r = rel + (size_t)rels[i] * HH;
    int j = lane * 2;
    ushort2 hru = *(const ushort2*)(h + j), hiu = *(const ushort2*)(h + 128 + j);
    ushort2 tru = *(const ushort2*)(t + j), tiu = *(const ushort2*)(t + 128 + j);
    float2 rr = *(const float2*)(r + j), ri = *(const float2*)(r + 128 + j);
    float hr0 = b2f(hru.x), hr1 = b2f(hru.y), hi0 = b2f(hiu.x), hi1 = b2f(hiu.y);
    float tr0 = b2f(tru.x), tr1 = b2f(tru.y), ti0 = b2f(tiu.x), ti1 = b2f(tiu.y);
    float acc = hr0 * rr.x * tr0 + hi0 * rr.x * ti0
              + hr0 * ri.x * ti0 - hi0 * ri.x * tr0
              + hr1 * rr.y * tr1 + hi1 * rr.y * ti1
              + hr1 * ri.y * ti1 - hi1 * ri.y * tr1;
#pragma unroll
    for (int o = 1; o < 64; o <<= 1) acc += __shfl_xor(acc, o);
    if (lane == 0) out[i] = acc;
}

// ---------------------------------------------------------------------------
extern "C" void kernel_launch(void* const* d_in, const int* in_sizes, int n_in,
                              void* d_out, int out_size, void* d_ws, size_t ws_size,
                              hipStream_t stream)
{
    const float* ent_emb     = (const float*)d_in[0];
    const float* text_base   = (const float*)d_in[1];
    const float* text_proj_w = (const float*)d_in[2];
    const float* text_proj_b = (const float*)d_in[3];
    const float* ln_g        = (const float*)d_in[4];
    const float* ln_b        = (const float*)d_in[5];
    const float* comp1       = (const float*)d_in[6];
    const float* basis1      = (const float*)d_in[7];
    const float* root1       = (const float*)d_in[8];
    const float* bias1       = (const float*)d_in[9];
    const float* comp2       = (const float*)d_in[10];
    const float* basis2      = (const float*)d_in[11];
    const float* root2       = (const float*)d_in[12];
    const float* bias2       = (const float*)d_in[13];
    const float* rel_emb     = (const float*)d_in[14];
    const int*   edge_src    = (const int*)d_in[15];
    const int*   edge_dst    = (const int*)d_in[16];
    const int*   edge_type   = (const int*)d_in[17];
    const int*   heads       = (const int*)d_in[18];
    const int*   rels        = (const int*)d_in[19];
    const int*   tails       = (const int*)d_in[20];
    float* out = (float*)d_out;

    char* ws = (char*)d_ws;
    size_t off = 0;
    auto carve = [&](size_t bytes) -> void* {
        void* p = ws + off;
        off = (off + bytes + 255) & ~(size_t)255;
        return p;
    };
    unsigned short* x0b  = (unsigned short*)carve((size_t)NN * HH * 2);
    unsigned short* x1b  = (unsigned short*)carve((size_t)NN * HH * 2);
    unsigned short* y16  = (unsigned short*)carve((size_t)NN * NBB * HH * 2);
    unsigned short* tb16 = (unsigned short*)carve((size_t)NN * TDD * 2);
    unsigned short* W16  = (unsigned short*)carve((size_t)HH * TDD * 2);
    unsigned short* Bt1  = (unsigned short*)carve((size_t)HH * 2304 * 2);
    unsigned short* Bt2  = (unsigned short*)carve((size_t)HH * 2304 * 2);
    int*   cnt     = (int*)  carve((size_t)NN * 4);
    int*   rp      = (int*)  carve((size_t)(NN + 1) * 4);
    int*   cur     = (int*)  carve((size_t)NN * 4);
    float* invdeg  = (float*)carve((size_t)NN * 4);
    int*   csr_src = (int*)  carve((size_t)EE * 4);
    int*   csr_et  = (int*)  carve((size_t)EE * 4);
    int*   bsum    = (int*)  carve(256 * 4);
    int*   boff    = (int*)  carve(256 * 4);

    const dim3 blk(256);
    const int NBLK = (NN + 255) / 256;
    const dim3 gemm_grid((NN + 127) / 128, 2);   // 391 x 2

    // ---- CSR build ----
    hipMemsetAsync(cnt, 0, (size_t)NN * 4, stream);
    hist_k<<<(EE + 255) / 256, blk, 0, stream>>>(edge_dst, cnt);
    scan_blk_k<<<NBLK, blk, 0, stream>>>(cnt, rp, bsum);
    scan_top_k<<<1, blk, 0, stream>>>(bsum, boff, NBLK);
    scan_add_k<<<NBLK, blk, 0, stream>>>(rp, boff, cur, cnt, invdeg);
    scatter_k<<<(EE + 255) / 256, blk, 0, stream>>>(
        edge_src, edge_dst, edge_type, cur, csr_src, csr_et);

    // ---- casts ----
    cast4_k<<<(NN * TDD / 4 + 255) / 256, blk, 0, stream>>>(text_base, tb16, NN * TDD / 4);
    cast4_k<<<(HH * TDD / 4 + 255) / 256, blk, 0, stream>>>(text_proj_w, W16, HH * TDD / 4);
    tcast_k<<<dim3(4, 4, 18), blk, 0, stream>>>(basis1, root1, basis2, root2, Bt1, Bt2);

    // ---- proj: x1b = bf16(tb @ W^T + ent_emb + b) ; x0b = LN(x1b) ----
    gemm16_k<1><<<gemm_grid, blk, 0, stream>>>(
        tb16, TDD, tb16, TDD, TDD, W16, TDD, x1b, NN, ent_emb, text_proj_b);
    ln_k<<<(NN + 3) / 4, blk, 0, stream>>>(x1b, x0b, ln_g, ln_b);

    // ---- two RGCN layers ----
    for (int layer = 0; layer < 2; ++layer) {
        const unsigned short* xin  = layer ? x1b : x0b;
        unsigned short*       xout = layer ? x0b : x1b;
        const unsigned short* Bt   = layer ? Bt2 : Bt1;
        const float*          comp = layer ? comp2 : comp1;
        const float*          bias = layer ? bias2 : bias1;

        agg_k<<<(NN + 3) / 4, blk, 0, stream>>>(
            xin, comp, rp, csr_src, csr_et, invdeg, y16);

        gemm16_k<2><<<gemm_grid, blk, 0, stream>>>(
            y16, NBB * HH, xin, HH, NBB * HH, Bt, NBB * HH + HH,
            xout, NN, nullptr, bias);
    }

    // ---- scoring ----
    score_k<<<(TTT + 3) / 4, blk, 0, stream>>>(x0b, rel_emb, heads, rels, tails, out);
}